// Round 10
// baseline (650.671 us; speedup 1.0000x reference)
//
#include <hip/hip_runtime.h>

// CrossAtt via Gram trick: logits = Wk·(x1·x2^T)·Wq^T; out = (attn^T·Wv)·x.
// Round 10: conv switched to mfma_f32_32x32x16_bf16 (half the MFMA issue slots,
// +15% per-instr FLOP rate). Staging/pipeline/vmcnt identical to r9; only frag
// reads + MFMA + epilogue mapping change. Everything else = r9.

typedef unsigned short u16;
typedef unsigned int u32;
typedef float f32x4 __attribute__((ext_vector_type(4)));
typedef float f32x16 __attribute__((ext_vector_type(16)));
typedef short bf16x8 __attribute__((ext_vector_type(8)));

#define DEV __device__ __forceinline__

DEV u16 f2bf(float f) {
  u32 u = __float_as_uint(f);
  return (u16)((u + 0x7fffu + ((u >> 16) & 1u)) >> 16);  // RNE
}
DEV float bf2f(u16 u) { return __uint_as_float(((u32)u) << 16); }

DEV void gload_lds16(const void* g, void* l) {
  __builtin_amdgcn_global_load_lds(
      (const __attribute__((address_space(1))) void*)g,
      (__attribute__((address_space(3))) void*)l, 16, 0, 0);
}

// stage a 128x32 bf16 tile; LDS slot s of row r holds global slot s^(r&3)
DEV void stage_tile(u16* L, const u16* src, int row0, long ld, int k0, int wid, int lane) {
  int rr = lane >> 2;
  int cc = (((lane & 3) ^ (rr & 3)) << 3);
#pragma unroll
  for (int j = 0; j < 2; ++j) {
    int chunk = j * 4 + wid;
    const u16* g = src + (long)(row0 + chunk * 16 + rr) * ld + (k0 + cc);
    gload_lds16(g, L + chunk * 512);
  }
}

DEV float waveRedSum(float v) {
#pragma unroll
  for (int o = 32; o > 0; o >>= 1) v += __shfl_xor(v, o);
  return v;
}

// ---------------- Gram GEMM, split-K=4 (unchanged) ----------------
__global__ __launch_bounds__(256) void gemm_gramK(const float* __restrict__ X1,
                                                  const float* __restrict__ X2,
                                                  float* __restrict__ parts)
{
  __shared__ __align__(16) u16 lds[4 * 4096];
  const int bid = blockIdx.x;
  const int cid = ((bid & 7) << 6) + (bid >> 3);
  const int z = cid >> 4, xy = cid & 15;
  const int quarter = z >> 3, b = z & 7;
  const int m0 = (xy & 3) * 128, n0 = (xy >> 2) * 128;
  const int tid = threadIdx.x, wid = tid >> 6, lane = tid & 63;
  const int wr = wid >> 1, wc = wid & 1;
  const int r16 = lane & 15;
  const int koff = (((lane >> 4) ^ (r16 & 3)) << 3);
  const float* A = X1 + (long)b * 2097152 + quarter * 1024;
  const float* Bp = X2 + (long)b * 2097152 + quarter * 1024;
  const int sr = tid >> 3;
  const int sc = (tid & 7) * 4;
  const int s8 = (tid & 7) >> 1, hf = tid & 1;
  const int swoff = ((s8 ^ (sr & 3)) << 3) + hf * 4;

  f32x4 acc[4][4];
#pragma unroll
  for (int i = 0; i < 4; ++i)
#pragma unroll
    for (int j = 0; j < 4; ++j) acc[i][j] = (f32x4){0.f, 0.f, 0.f, 0.f};

  for (int k0 = 0; k0 < 1024; k0 += 32) {
    __syncthreads();
#pragma unroll
    for (int rr = 0; rr < 128; rr += 32) {
      float4 va = *(const float4*)&A[(long)(m0 + rr + sr) * 4096 + k0 + sc];
      float4 vb = *(const float4*)&Bp[(long)(n0 + rr + sr) * 4096 + k0 + sc];
      float fa[4] = {va.x, va.y, va.z, va.w};
      float fb[4] = {vb.x, vb.y, vb.z, vb.w};
      u32 pah0 = 0, pah1 = 0, pal0 = 0, pal1 = 0;
      u32 pbh0 = 0, pbh1 = 0, pbl0 = 0, pbl1 = 0;
#pragma unroll
      for (int e = 0; e < 2; ++e) {
        u16 h = f2bf(fa[e]);      pah0 |= ((u32)h) << (16 * e);
        u16 lo = f2bf(fa[e] - bf2f(h)); pal0 |= ((u32)lo) << (16 * e);
        h = f2bf(fa[e + 2]);      pah1 |= ((u32)h) << (16 * e);
        lo = f2bf(fa[e + 2] - bf2f(h)); pal1 |= ((u32)lo) << (16 * e);
        h = f2bf(fb[e]);          pbh0 |= ((u32)h) << (16 * e);
        lo = f2bf(fb[e] - bf2f(h)); pbl0 |= ((u32)lo) << (16 * e);
        h = f2bf(fb[e + 2]);      pbh1 |= ((u32)h) << (16 * e);
        lo = f2bf(fb[e + 2] - bf2f(h)); pbl1 |= ((u32)lo) << (16 * e);
      }
      int off = (rr + sr) * 32 + swoff;
      *(uint2*)&lds[off]         = make_uint2(pah0, pah1);
      *(uint2*)&lds[4096 + off]  = make_uint2(pal0, pal1);
      *(uint2*)&lds[8192 + off]  = make_uint2(pbh0, pbh1);
      *(uint2*)&lds[12288 + off] = make_uint2(pbl0, pbl1);
    }
    __syncthreads();
    bf16x8 ah[4], al[4], bh[4], bl[4];
#pragma unroll
    for (int mi = 0; mi < 4; ++mi) {
      ah[mi] = *(const bf16x8*)&lds[(wr * 64 + mi * 16 + r16) * 32 + koff];
      al[mi] = *(const bf16x8*)&lds[4096 + (wr * 64 + mi * 16 + r16) * 32 + koff];
    }
#pragma unroll
    for (int nj = 0; nj < 4; ++nj) {
      bh[nj] = *(const bf16x8*)&lds[8192 + (wc * 64 + nj * 16 + r16) * 32 + koff];
      bl[nj] = *(const bf16x8*)&lds[12288 + (wc * 64 + nj * 16 + r16) * 32 + koff];
    }
#pragma unroll
    for (int mi = 0; mi < 4; ++mi)
#pragma unroll
      for (int nj = 0; nj < 4; ++nj) {
        acc[mi][nj] = __builtin_amdgcn_mfma_f32_16x16x32_bf16(ah[mi], bh[nj], acc[mi][nj], 0, 0, 0);
        acc[mi][nj] = __builtin_amdgcn_mfma_f32_16x16x32_bf16(ah[mi], bl[nj], acc[mi][nj], 0, 0, 0);
        acc[mi][nj] = __builtin_amdgcn_mfma_f32_16x16x32_bf16(al[mi], bh[nj], acc[mi][nj], 0, 0, 0);
      }
  }

  const int rq = lane >> 4;
  float* O = parts + (long)z * 262144;
#pragma unroll
  for (int mi = 0; mi < 4; ++mi)
#pragma unroll
    for (int nj = 0; nj < 4; ++nj)
#pragma unroll
      for (int i = 0; i < 4; ++i) {
        int row = m0 + wr * 64 + mi * 16 + rq * 4 + i;
        int col = n0 + wc * 64 + nj * 16 + r16;
        O[(long)row * 512 + col] = acc[mi][nj][i];
      }
}

__global__ __launch_bounds__(256) void k_gsplit(const float* __restrict__ parts,
                                                u16* __restrict__ Gh, u16* __restrict__ Gl)
{
  for (long i = (long)blockIdx.x * 256 + threadIdx.x; i < 2097152; i += (long)gridDim.x * 256) {
    float v = parts[i] + parts[i + 2097152] + parts[i + 4194304] + parts[i + 6291456];
    u16 h = f2bf(v);
    Gh[i] = h;
    Gl[i] = f2bf(v - bf2f(h));
  }
}

// ---------------- branch-merged TN GEMM (unchanged) ----------------
constexpr int EP_SPLIT = 0, EP_LOGITS = 1, EP_BF16 = 2, EP_XCAT = 3;

struct GArgs {
  const u16* Ah[2]; const u16* Al[2];
  const u16* Bh[2]; const u16* Bl[2];
  long Az[2], Bz[2];
  void* O0[2]; void* O1[2];
  const float* f0[2]; const float* f1[2];
  const float* f2[2]; const float* f3[2];
  const u16* rptr[2];
};

template <int EP, bool SPLIT3, bool FLAT>
__global__ __launch_bounds__(256) void gemm_tn2(GArgs ga, int lda, int ldb, int K, long Oz)
{
  __shared__ __align__(16) u16 lds[(SPLIT3 ? 4 : 2) * 4096];
  int bx, by, z;
  if constexpr (FLAT) {
    const int cid = ((blockIdx.x & 7) << 8) + (blockIdx.x >> 3);
    z = cid >> 7;
    const int xy = cid & 127;
    bx = xy >> 2; by = xy & 3;
  } else {
    bx = blockIdx.x; by = blockIdx.y; z = blockIdx.z;
  }
  const int br = z >> 3, b = z & 7;
  const u16* pAh = ga.Ah[br] + (long)b * ga.Az[br];
  const u16* pBh = ga.Bh[br] + (long)b * ga.Bz[br];
  const u16* pAl = SPLIT3 ? ga.Al[br] + (long)b * ga.Az[br] : nullptr;
  const u16* pBl = SPLIT3 ? ga.Bl[br] + (long)b * ga.Bz[br] : nullptr;
  const int m0 = bx * 128, n0 = by * 128;
  const int tid = threadIdx.x, wid = tid >> 6, lane = tid & 63;
  const int wr = wid >> 1, wc = wid & 1;
  const int r16 = lane & 15;
  const int koff = (((lane >> 4) ^ (r16 & 3)) << 3);

  f32x4 acc[4][4];
#pragma unroll
  for (int i = 0; i < 4; ++i)
#pragma unroll
    for (int j = 0; j < 4; ++j) acc[i][j] = (f32x4){0.f, 0.f, 0.f, 0.f};

  for (int k0 = 0; k0 < K; k0 += 32) {
    __syncthreads();
    stage_tile(lds, pAh, m0, lda, k0, wid, lane);
    stage_tile(lds + 4096, pBh, n0, ldb, k0, wid, lane);
    if constexpr (SPLIT3) {
      stage_tile(lds + 8192, pAl, m0, lda, k0, wid, lane);
      stage_tile(lds + 12288, pBl, n0, ldb, k0, wid, lane);
    }
    __syncthreads();
    bf16x8 af[4], bfh[4], af2[4], bf2_[4];
#pragma unroll
    for (int mi = 0; mi < 4; ++mi)
      af[mi] = *(const bf16x8*)&lds[(wr * 64 + mi * 16 + r16) * 32 + koff];
#pragma unroll
    for (int nj = 0; nj < 4; ++nj)
      bfh[nj] = *(const bf16x8*)&lds[4096 + (wc * 64 + nj * 16 + r16) * 32 + koff];
    if constexpr (SPLIT3) {
#pragma unroll
      for (int mi = 0; mi < 4; ++mi)
        af2[mi] = *(const bf16x8*)&lds[8192 + (wr * 64 + mi * 16 + r16) * 32 + koff];
#pragma unroll
      for (int nj = 0; nj < 4; ++nj)
        bf2_[nj] = *(const bf16x8*)&lds[12288 + (wc * 64 + nj * 16 + r16) * 32 + koff];
    }
#pragma unroll
    for (int mi = 0; mi < 4; ++mi)
#pragma unroll
      for (int nj = 0; nj < 4; ++nj) {
        acc[mi][nj] = __builtin_amdgcn_mfma_f32_16x16x32_bf16(af[mi], bfh[nj], acc[mi][nj], 0, 0, 0);
        if constexpr (SPLIT3) {
          acc[mi][nj] = __builtin_amdgcn_mfma_f32_16x16x32_bf16(af[mi], bf2_[nj], acc[mi][nj], 0, 0, 0);
          acc[mi][nj] = __builtin_amdgcn_mfma_f32_16x16x32_bf16(af2[mi], bfh[nj], acc[mi][nj], 0, 0, 0);
        }
      }
  }

  const int rq = lane >> 4;
  const long off = (long)z * Oz;
  float g = 0.f;
  if constexpr (EP == EP_XCAT) g = ga.f1[br][b];
#pragma unroll
  for (int mi = 0; mi < 4; ++mi)
#pragma unroll
    for (int nj = 0; nj < 4; ++nj)
#pragma unroll
      for (int i = 0; i < 4; ++i) {
        int row = m0 + wr * 64 + mi * 16 + rq * 4 + i;
        int col = n0 + wc * 64 + nj * 16 + r16;
        float v = acc[mi][nj][i];
        if constexpr (EP == EP_SPLIT) {
          long idx = off + (long)row * 512 + col;
          u16 h = f2bf(v);
          ((u16*)ga.O0[br])[idx] = h;
          ((u16*)ga.O1[br])[idx] = f2bf(v - bf2f(h));
        } else if constexpr (EP == EP_LOGITS) {
          v += ga.f0[br][row] * ga.f3[br][b * 512 + col] + ga.f1[br][col] * ga.f2[br][b * 512 + row];
          ((float*)ga.O0[br])[off + (long)row * 512 + col] = v;
        } else if constexpr (EP == EP_BF16) {
          ((u16*)ga.O0[br])[off + (long)row * 512 + col] = f2bf(v);
        } else {
          float val = (v + ga.f0[br][b * 512 + col]) * g +
                      bf2f(ga.rptr[br][(long)b * 2097152 + (long)row * 512 + col]);
          int yy = row >> 6, xx = row & 63;
          long oidx = ((long)(b * 66 + yy + 1) * 66 + (xx + 1)) * 512 + col;
          ((u16*)ga.O0[br])[oidx] = f2bf(val);
        }
      }
}

// ---------------- conv3x3: pipelined, 32x32x16 MFMA ----------------
#define MF32(a, b, c) __builtin_amdgcn_mfma_f32_32x32x16_bf16(a, b, c, 0, 0, 0)
#define SCHEDB() __builtin_amdgcn_sched_barrier(0)
#define BAR() __builtin_amdgcn_s_barrier()
#define STG_B(QB, i) gload_lds16(xb + sbo[i] + kko, &lds[(QB) + ldsB0 + (i) * 4096])
#define STG_A(QB, i) gload_lds16(Arow + (i) * 294912L + Aoff, &lds[(QB) + ldsA0 + (i) * 2048])

// read 32-row A frag jj at 4 k-quarters (swizzled slots)
#define RD_A32(d, jj)                                                       \
  d##0 = *(const bf16x8*)&lds[pBase + aBase + (jj) * 2048 + sxk0];          \
  d##1 = *(const bf16x8*)&lds[pBase + aBase + (jj) * 2048 + sxk1];          \
  d##2 = *(const bf16x8*)&lds[pBase + aBase + (jj) * 2048 + sxk2];          \
  d##3 = *(const bf16x8*)&lds[pBase + aBase + (jj) * 2048 + sxk3];

// 8 MFMA: row-frag jj x {2 col-frags} x {4 k-quarters}, cf-interleaved for ILP
#define MM32(jj, r)                                                         \
  __builtin_amdgcn_s_setprio(1);                                            \
  acc[jj][0] = MF32(r##0, bq[0][0], acc[jj][0]);                            \
  acc[jj][1] = MF32(r##0, bq[1][0], acc[jj][1]);                            \
  acc[jj][0] = MF32(r##1, bq[0][1], acc[jj][0]);                            \
  acc[jj][1] = MF32(r##1, bq[1][1], acc[jj][1]);                            \
  acc[jj][0] = MF32(r##2, bq[0][2], acc[jj][0]);                            \
  acc[jj][1] = MF32(r##2, bq[1][2], acc[jj][1]);                            \
  acc[jj][0] = MF32(r##3, bq[0][3], acc[jj][0]);                            \
  acc[jj][1] = MF32(r##3, bq[1][3], acc[jj][1]);                            \
  __builtin_amdgcn_s_setprio(0);                                            \
  SCHEDB();

__global__ __launch_bounds__(512, 2) void k_conv32(const u16* __restrict__ W,
                                                   const u16* __restrict__ xA,
                                                   const u16* __restrict__ xB,
                                                   float* __restrict__ y,
                                                   float* __restrict__ bnsum,
                                                   float* __restrict__ bnsum2)
{
  __shared__ __align__(16) u16 lds[65536];
  const int cid = ((blockIdx.x & 7) << 5) + (blockIdx.x >> 3);
  const int bz = cid >> 5, mx = (cid >> 4) & 1, ny = cid & 15;
  const int m0 = mx * 256, n0 = ny * 256;
  const long zoff = (long)bz * 2230272;

  const int tid = threadIdx.x;
  const int w = tid >> 6, l = tid & 63;
  const int wr = w >> 2, wcn = w & 3, wl = w & 3;
  const int lr = l >> 3, l7 = l & 7, l31 = l & 31, l5 = l >> 5;
  const int ss8 = (l7 ^ lr) << 3;

  long sbo[4];
#pragma unroll
  for (int i = 0; i < 4; ++i) {
    int n = n0 + i * 64 + w * 8 + lr;
    sbo[i] = (long)((n >> 6) * 66 + (n & 63)) * 512;
  }
  const u16* Arow = W + (long)(m0 + wr * 128 + wl * 8 + lr) * 9216 + ss8;
  const int ldsA0 = wr * 8192 + wl * 512;
  const int ldsB0 = 16384 + w * 512;
  // 32x32x16 frag addressing: row = lane&31, k-slot = 2*kq + (lane>>5), XOR row&7
  const int sxk0 = ((0 + l5) ^ l7) << 3;
  const int sxk1 = ((2 + l5) ^ l7) << 3;
  const int sxk2 = ((4 + l5) ^ l7) << 3;
  const int sxk3 = ((6 + l5) ^ l7) << 3;
  const int aBase = wr * 8192 + l31 * 64;
  const int bBase = 16384 + wcn * 4096 + l31 * 64;

  f32x16 acc[4][2];
#pragma unroll
  for (int i = 0; i < 4; ++i)
#pragma unroll
    for (int j = 0; j < 2; ++j)
#pragma unroll
      for (int e = 0; e < 16; ++e) acc[i][j][e] = 0.f;

  {
    const u16* xb = xA + zoff;
    const long kko = ss8;
    const long Aoff = 0;
    STG_B(0, 0); STG_B(0, 1); STG_B(0, 2); STG_B(0, 3);
    STG_A(0, 0); STG_A(0, 1); STG_A(0, 2); STG_A(0, 3);
  }

  for (int t = 0; t < 144; ++t) {
    const int pBase = (t & 1) << 15;
    const int qBase = pBase ^ 32768;
    const int tau = t + 1;
    const bool pf = tau < 144;
    const int ccc = tau / 9;
    const int tap = tau - ccc * 9;
    const int cch = ccc << 6;
    const u16* xb = ((cch & 512) ? xB : xA) + zoff;
    const long kko = (long)((tap / 3) * 66 + (tap % 3)) * 512 + (cch & 511) + ss8;
    const long Aoff = (long)(tap << 10) + cch;
    bf16x8 bq[2][4];
    bf16x8 cA0, cA1, cA2, cA3, nA0, nA1, nA2, nA3;

    // phase 0: consume B0-3 + A-line 0, prefetch A-line 1
    if (pf) { STG_B(qBase, 0); STG_B(qBase, 1); asm volatile("s_waitcnt vmcnt(4)" ::: "memory"); }
    else    { asm volatile("s_waitcnt vmcnt(2)" ::: "memory"); }
    BAR(); SCHEDB();
#pragma unroll
    for (int cf = 0; cf < 2; ++cf) {
      bq[cf][0] = *(const bf16x8*)&lds[pBase + bBase + cf * 2048 + sxk0];
      bq[cf][1] = *(const bf16x8*)&lds[pBase + bBase + cf * 2048 + sxk1];
      bq[cf][2] = *(const bf16x8*)&lds[pBase + bBase + cf * 2048 + sxk2];
      bq[cf][3] = *(const bf16x8*)&lds[pBase + bBase + cf * 2048 + sxk3];
    }
    RD_A32(cA, 0)
    RD_A32(nA, 1)
    MM32(0, cA)
    // phase 1
    if (pf) { STG_B(qBase, 2); STG_B(qBase, 3); asm volatile("s_waitcnt vmcnt(5)" ::: "memory"); }
    else    { asm volatile("s_waitcnt vmcnt(1)" ::: "memory"); }
    BAR(); SCHEDB();
    RD_A32(cA, 2)
    MM32(1, nA)
    // phase 2
    if (pf) { STG_A(qBase, 0); STG_A(qBase, 1); asm volatile("s_waitcnt vmcnt(6)" ::: "memory"); }
    else    { asm volatile("s_waitcnt vmcnt(0)" ::: "memory"); }
    BAR(); SCHEDB();
    RD_A32(nA, 3)
    MM32(2, cA)
    // phase 3
    if (pf) { STG_A(qBase, 2); STG_A(qBase, 3); }
    BAR(); SCHEDB();
    MM32(3, nA)
  }

  // y write: C/D: col = lane&31, row = (reg&3) + 8*(reg>>2) + 4*(lane>>5)
#pragma unroll
  for (int j = 0; j < 4; ++j)
#pragma unroll
    for (int cf = 0; cf < 2; ++cf)
#pragma unroll
      for (int reg = 0; reg < 16; ++reg) {
        int row = m0 + wr * 128 + j * 32 + (reg & 3) + 8 * (reg >> 2) + 4 * l5;
        int col = n0 + wcn * 64 + cf * 32 + l31;
        y[((long)bz * 512 + row) * 4096 + col] = acc[j][cf][reg];
      }

  // fused BN partial stats
  __syncthreads();
  float* fl = (float*)lds;
#pragma unroll
  for (int j = 0; j < 4; ++j)
#pragma unroll
    for (int reg = 0; reg < 16; ++reg) {
      float s = acc[j][0][reg] + acc[j][1][reg];
      float s2 = acc[j][0][reg] * acc[j][0][reg] + acc[j][1][reg] * acc[j][1][reg];
#pragma unroll
      for (int m = 1; m < 32; m <<= 1) { s += __shfl_xor(s, m); s2 += __shfl_xor(s2, m); }
      if (l31 == 0) {
        int r = wr * 128 + j * 32 + (reg & 3) + 8 * (reg >> 2) + 4 * l5;
        fl[r * 4 + wcn] = s;
        fl[1024 + r * 4 + wcn] = s2;
      }
    }
  __syncthreads();
  {
    int r = tid & 255;
    int which = tid >> 8;
    const float* p = fl + which * 1024 + r * 4;
    float v = p[0] + p[1] + p[2] + p[3];
    atomicAdd((which ? bnsum2 : bnsum) + m0 + r, v);
  }
}

// ---------------- mega-prep (unchanged) ----------------
struct PrepArgs {
  const float* wv1; const float* wv2;
  u16* WvT1; u16* WvT2;
  const float* s[4]; u16* h[4]; u16* l[4];
  const float* wcat; u16* wcp;
  u16* xcat;
  float* rsum; float* bnsum; float* mbz;
};

__global__ __launch_bounds__(256) void k_mprep(PrepArgs a)
{
  __shared__ __align__(16) float shbuf[9261];
  const int bx = blockIdx.x;
  const int tid = threadIdx.x;
  if (bx < 128) {
    const float* src = (bx < 64) ? a.wv1 : a.wv2;
    u16* dst = (bx < 64) ? a.WvT1 : a.WvT2;
    const int t8 = bx & 63;
    const int c0 = (t8 & 7) * 64, r0 = (t8 >> 3) * 64;
#pragma unroll
    for (int it = 0; it < 4; ++it) {
      int rr = it * 16 + (tid >> 4);
      int cc = (tid & 15) * 4;
      float4 v = *(const float4*)&src[(long)(r0 + rr) * 512 + c0 + cc];
      shbuf[rr * 65 + cc] = v.x; shbuf[rr * 65 + cc + 1] = v.y;
      shbuf[rr * 65 + cc + 2] = v.z; shbuf[rr * 65 + cc + 3] = v.w;
    }
    __syncthreads();
    int nr = tid >> 2, cs = (tid & 3) * 16;
    u16 hh[16] __attribute__((aligned(16)));
#pragma unroll
    for (int j = 0; j < 16; ++j) hh[j] = f2bf(shbuf[(cs + j) * 65 + nr]);
    long d = (long)(c0 + nr) * 512 + r0 + cs;
    *(uint4*)&dst[d] = *(const uint4*)&hh[0];
    *(uint4*)&dst[d + 8] = *(const uint4*)&hh[8];
  } else if (bx < 1152) {
    int which = (bx - 128) >> 8;
    const float* s = a.s[which];
    u16* h = a.h[which];
    u16* l = a.l[which];
    for (int i = ((bx - 128) & 255) * 256 + tid; i < 262144; i += 65536) {
      float v = s[i];
      u16 hh = f2bf(v);
      h[i] = hh;
      l[i] = f2bf(v - bf2f(hh));
    }
  } else if (bx < 1664) {
    const int o = bx - 1152;
    const float* s = a.wcat + (long)o * 9216;
#pragma unroll
    for (int it = 0; it < 9; ++it) {
      int f4 = it * 256 + tid;
      float4 v = *(const float4*)&s[f4 * 4];
      float va[4] = {v.x, v.y, v.z, v.w};
      int f = f4 * 4;
#pragma unroll
      for (int e = 0; e < 4; ++e) {
        int ic = (f + e) / 9, tp = (f + e) - ic * 9;
        shbuf[tp * 1029 + ic] = va[e];
      }
    }
    __syncthreads();
    u16* d = a.wcp + (long)o * 9216;
#pragma unroll
    for (int tp = 0; tp < 9; ++tp)
#pragma unroll
      for (int c = 0; c < 4; ++c) {
        int ic = c * 256 + tid;
        d[tp * 1024 + ic] = f2bf(shbuf[tp * 1029 + ic]);
      }
  } else if (bx < 1680) {
    const long base = (long)(bx - 1664) * 2230272;
    const uint4 z4 = make_uint4(0, 0, 0, 0);
    for (int i = tid; i < 8448; i += 256) {
      long off = (i < 4224) ? (long)i * 8 : (long)65 * 66 * 512 + (long)(i - 4224) * 8;
      *(uint4*)&a.xcat[base + off] = z4;
    }
    for (int i = tid; i < 8192; i += 256) {
      int y = 1 + (i >> 7);
      int xsel = (i >> 6) & 1;
      int v = i & 63;
      long off = ((long)y * 66 + (xsel ? 65 : 0)) * 512 + (long)v * 8;
      *(uint4*)&a.xcat[base + off] = z4;
    }
  } else {
    float4 f4 = {0.f, 0.f, 0.f, 0.f};
    for (int i = tid; i < 2048; i += 256) ((float4*)a.rsum)[i] = f4;
    for (int i = tid; i < 256; i += 256) ((float4*)a.bnsum)[i] = f4;
    for (int i = tid; i < 2048; i += 256) ((float4*)a.mbz)[i] = f4;
  }
}

// ---------------- prep: transpose both inputs + gate rowsums (unchanged) ----------------
__global__ __launch_bounds__(256) void k_prep(const float* __restrict__ in1,
                                              const float* __restrict__ in2,
                                              u16* __restrict__ xT1, u16* __restrict__ xT2,
                                              float* __restrict__ rsum)
{
  __shared__ float t[64][65];
  const int zz = blockIdx.z;
  const int inp = zz >> 3, b = zz & 7;
  const int cb = blockIdx.y, nb = blockIdx.x;
  const float* s = (inp ? in2 : in1) + (long)b * 2097152;
  u16* xT = inp ? xT2 : xT1;
  float* rs = rsum + inp * 4096;
  const int tid = threadIdx.x;
#pragma unroll
  for (int it = 0; it < 4; ++it) {
    int cr = it * 16 + (tid >> 4);
    int nc = (tid & 15) * 4;
    float4 v = *(const float4*)&s[(long)(cb * 64 + cr) * 4096 + nb * 64 + nc];
    t[cr][nc] = v.x; t[cr][nc + 1] = v.y; t[cr][nc + 2] = v.z; t[cr][nc + 3] = v.w;
  }
  __syncthreads();
  int nr = tid >> 2, cs = (tid & 3) * 16;
  u16 hh[16] __attribute__((aligned(16)));
#pragma unroll
  for (int j = 0; j < 16; ++j) hh[j] = f2bf(t[cs + j][nr]);
  long d = (long)b * 2097152 + (long)(nb * 64 + nr) * 512 + cb * 64 + cs;
  *(uint4*)&xT[d] = *(const uint4*)&hh[0];
  *(uint4*)&xT[d + 8] = *(const uint4*)&hh[8];
  if (tid < 64) {
    float sum = 0.f;
#pragma unroll 8
    for (int j = 0; j < 64; ++j) sum += t[tid][j];
    atomicAdd(&rs[b * 512 + tid + cb * 64], sum);
  }
}

// ---------------- skq + gate (unchanged) ----------------
__global__ __launch_bounds__(256) void k_skq(const float* __restrict__ wk1, const float* __restrict__ wq2,
                                             const float* __restrict__ wk2, const float* __restrict__ wq1,
                                             const float* __restrict__ bq2, const float* __restrict__ bq1,
                                             const float* __restrict__ wlin,
                                             const float* __restrict__ rowsum,
                                             float* __restrict__ S, float* __restrict__ gates)
{
  int which = blockIdx.y, b = blockIdx.z;
  int lane = threadIdx.x & 63;
  if (which == 4) {
    if (blockIdx.x < 2 && threadIdx.x < 64) {
      int inp = blockIdx.x;
      float s = 0.f;
      for (int c = lane; c < 512; c += 64) s += rowsum[inp * 4096 + b * 512 + c] * wlin[c];
      s = waveRedSum(s);
      if (lane == 0) gates[inp * 8 + b] = 1.f / (1.f + __expf(-s / 4096.f));
    }
    return;
  }
  int row = blockIdx.x * 4 + (threadIdx.x >> 6);
  const float* W; const float* rs; const float* bias = nullptr;
  if (which == 0)      { W = wk1; rs = rowsum + b * 512; }
  else if (which == 1) { W = wq2; rs = rowsum + 4096 + b * 512; bias = bq2; }
  else if (which == 2) { W = wk2; rs = rowsum + 4096 + b * 512; }
  else                 { W = wq1; rs = rowsum + b * 512; bias = bq1; }
  float s = 0.f;
  for (int i = lane; i < 512; i += 64) s += W[row * 512 + i] * rs[i];
  s = waveRedSum(s);
  if (lane == 0) S[(which * 8 + b) * 512 + row] = s + (bias ? 4096.f * bias[row] : 0.f);
}

// ---------------- softmax + fused mbias partials (unchanged) ----------------
__global__ __launch_bounds__(256) void k_softmaxT(const float* __restrict__ L,
                                                  u16* __restrict__ attnT,
                                                  const float* __restrict__ bv1,
                                                  const float* __restrict__ bv2,
                                                  float* __restrict__ mb)
{
  const int bid = blockIdx.x;
  const int z = bid >> 4, rg = bid & 15;
  const int w = threadIdx.x >> 6, lane = threadIdx.x & 63;
  const int a0 = rg * 32 + w * 8;
  const float* Lz = L + (long)z * 262144;
  const float* bv = (z >= 8) ? bv2 : bv1;
  u16* Az = attnT + (long)z * 262144;
  u32 pk[8][4] = {};
  float pmb[8] = {};
#pragma unroll
  for (int it = 0; it < 8; ++it) {
    long base = (long)(a0 + it) * 512 + lane * 8;
    float4 p0 = *(const float4*)&Lz[base], p1 = *(const float4*)&Lz[base + 4];
    float v[8] = {p0.x, p0.y, p0.z, p0.w, p1.x, p1.y, p1.z, p1.w};
    float m = v[0];
#pragma unroll
    for (int j = 1; j < 8; ++j) m = fmaxf(m, v[j]);
#pragma unroll
    for (int o = 32; o > 0; o >>= 1) m = fmaxf(m, __shfl_xor(m, o));
    float e[8], s = 0.f;
#pragma unroll
    for (int j = 0; j < 8; ++j) { e[j] = __expf(v[j] - m); s += e[j]; }
    s = waveRedSum(s);
    float inv = 1.f / s;
    float bvv = bv[a0 + it];
#pragma unroll
    for (int j = 0; j < 8; ++j) {
      float p = e[j] * inv;
      pk[j][it >> 1] |= ((u32)f2bf(p)) << ((it & 1) * 16);
      pmb[j] += p * bvv;
    }
  }
#pragma unroll
  for (int j = 0; j < 8; ++j) {
    int c = lane * 8 + j;
    *(uint4*)&Az[(long)c * 512 + a0] = make_uint4(pk[j][0], pk[j][1], pk[j][2], pk[j][3]);
    atomicAdd(&mb[z * 512 + c], pmb[j]);
  }
}

// ---------------- BN apply (stats inlined) + ReLU (unchanged) ----------------
__global__ __launch_bounds__(256) void k_bnapply(float* __restrict__ y,
                                                 const float* __restrict__ bnsum,
                                                 const float* __restrict__ bnsum2,
                                                 const float* __restrict__ gamma,
                                                 const float* __restrict__ beta)
{
  const long n = 16777216;
  for (long i = ((long)blockIdx.x * 256 + threadIdx.x) * 4; i < n; i += (long)gridDim.x * 1024) {
    float4 v = *(const float4*)&y[i];
    int o = (int)((i >> 12) & 511);
    float mean = bnsum[o] * (1.f / 32768.f);
    float var = bnsum2[o] * (1.f / 32768.f) - mean * mean;
    float a = gamma[o] * rsqrtf(var + 1e-5f);
    float c = beta[o] - mean * a;
    v.x = fmaxf(v.x * a + c, 0.f);
    v.y = fmaxf(v.y * a + c, 0.f);
    v.z = fmaxf(v.z * a + c, 0.f);
    v.w = fmaxf(v.w * a + c, 0.f);
    *(float4*)&y[i] = v;
  }
}

// ================= host =================
extern "C" void kernel_launch(void* const* d_in, const int* in_sizes, int n_in,
                              void* d_out, int out_size, void* d_ws, size_t ws_size,
                              hipStream_t stream)
{
  (void)in_sizes; (void)n_in; (void)out_size; (void)ws_size;
  const float* in1 = (const float*)d_in[0];
  const float* in2 = (const float*)d_in[1];
  const float* wq1 = (const float*)d_in[2];  const float* bq1 = (const float*)d_in[3];
  const float* wk1 = (const float*)d_in[4];  const float* bk1 = (const float*)d_in[5];
  const float* wv1 = (const float*)d_in[6];  const float* bv1 = (const float*)d_in[7];
  const float* wq2 = (const float*)d_in[8];  const float* bq2 = (const float*)d_in[9];
  const float* wk2 = (const float*)d_in[10]; const float* bk2 = (const float*)d_in[11];
  const float* wv2 = (const float*)d_in[12]; const float* bv2 = (const float*)d_in[13];
  const float* wlin  = (const float*)d_in[14];
  const float* wcat  = (const float*)d_in[15];
  const float* gamma = (const float*)d_in[16];
  const float* beta  = (const float*)d_in[17];

  char* ws = (char*)d_ws;
  const size_t MB = 1024ull * 1024ull;
  u16* Gh     = (u16*)(ws + 0 * MB);
  u16* Gl     = (u16*)(ws + 4 * MB);
  u16* Mb     = (u16*)(ws + 0 * MB);
  u16* Uh     = (u16*)(ws + 8 * MB);
  u16* attnT  = (u16*)(ws + 8 * MB);
  u16* Ul     = (u16*)(ws + 16 * MB);
  float* logits = (float*)(ws + 24 * MB);
  float* parts  = (float*)(ws + 8 * MB);
  u16* xcatA  = (u16*)(ws + 40 * MB);
  u16* xcatB  = xcatA + 8L * 2230272;
  u16* wcp    = (u16*)(ws + 112 * MB);
  u16* wsp    = (u16*)(ws + 122 * MB);
  u16* WvT1   = (u16*)(ws + 126 * MB);
  u16* WvT2   = WvT1 + 262144;
  float* rowsum = (float*)(ws + 127 * MB);
  float* gates  = (float*)(ws + 127 * MB + 32 * 1024);
  float* S      = (float*)(ws + 127 * MB + 36 * 1024);
  float* mb     = (float*)(ws + 127 * MB + 100 * 1024);
  float* bnsum  = (float*)(ws + 127 * MB + 132 * 1024);
  float* bnsum2 = (float*)(ws + 127 * MB + 134 * 1024);

  u16* wq1h = wsp + 0 * 262144; u16* wq1l = wsp + 1 * 262144;
  u16* wq2h = wsp + 2 * 262144; u16* wq2l = wsp + 3 * 262144;
  u16* wk1h = wsp + 4 * 262144; u16* wk1l = wsp + 5 * 262144;
  u16* wk2h = wsp + 6 * 262144; u16* wk2l = wsp + 7 * 262144;

  u16* xT1 = (u16*)d_out;
  u16* xT2 = (u16*)d_out + 16777216;
  float* ybuf = (float*)d_out;

  {
    PrepArgs pa;
    pa.wv1 = wv1; pa.wv2 = wv2; pa.WvT1 = WvT1; pa.WvT2 = WvT2;
    pa.s[0] = wq1; pa.h[0] = wq1h; pa.l[0] = wq1l;
    pa.s[1] = wq2; pa.h[1] = wq2h; pa.l[1] = wq2l;
    pa.s[2] = wk1; pa.h[2] = wk1h; pa.l[2] = wk1l;
    pa.s[3] = wk2; pa.h[3] = wk2h; pa.l[3] = wk2l;
    pa.wcat = wcat; pa.wcp = wcp;
    pa.xcat = xcatA;
    pa.rsum = rowsum; pa.bnsum = bnsum; pa.mbz = mb;
    k_mprep<<<1681, 256, 0, stream>>>(pa);
  }
  k_prep<<<dim3(64, 8, 16), 256, 0, stream>>>(in1, in2, xT1, xT2, rowsum);
  k_skq<<<dim3(128, 5, 8), 256, 0, stream>>>(wk1, wq2, wk2, wq1, bq2, bq1, wlin, rowsum, S, gates);

  gemm_gramK<<<512, 256, 0, stream>>>(in1, in2, parts);
  k_gsplit<<<2048, 256, 0, stream>>>(parts, Gh, Gl);

  {
    GArgs ga = {};
    ga.Ah[0] = wq2h; ga.Al[0] = wq2l; ga.Ah[1] = wk2h; ga.Al[1] = wk2l;
    ga.Az[0] = 0; ga.Az[1] = 0;
    ga.Bh[0] = Gh; ga.Bl[0] = Gl; ga.Bh[1] = Gh; ga.Bl[1] = Gl;
    ga.Bz[0] = 262144; ga.Bz[1] = 262144;
    ga.O0[0] = Uh; ga.O0[1] = Uh; ga.O1[0] = Ul; ga.O1[1] = Ul;
    gemm_tn2<EP_SPLIT, true, false><<<dim3(4, 4, 16), 256, 0, stream>>>(ga, 512, 512, 512, 262144);
  }
  {
    GArgs ga = {};
    ga.Ah[0] = wk1h; ga.Al[0] = wk1l; ga.Az[0] = 0;
    ga.Ah[1] = Uh + 2097152; ga.Al[1] = Ul + 2097152; ga.Az[1] = 262144;
    ga.Bh[0] = Uh; ga.Bl[0] = Ul; ga.Bz[0] = 262144;
    ga.Bh[1] = wq1h; ga.Bl[1] = wq1l; ga.Bz[1] = 0;
    ga.O0[0] = logits; ga.O0[1] = logits;
    ga.f0[0] = bk1; ga.f1[0] = bq2; ga.f2[0] = S;        ga.f3[0] = S + 4096;
    ga.f0[1] = bk2; ga.f1[1] = bq1; ga.f2[1] = S + 8192; ga.f3[1] = S + 12288;
    gemm_tn2<EP_LOGITS, true, false><<<dim3(4, 4, 16), 256, 0, stream>>>(ga, 512, 512, 512, 262144);
  }
  k_softmaxT<<<256, 256, 0, stream>>>(logits, attnT, bv1, bv2, mb);
  {
    GArgs ga = {};
    ga.Ah[0] = attnT; ga.Ah[1] = attnT + 2097152;
    ga.Az[0] = 262144; ga.Az[1] = 262144;
    ga.Bh[0] = WvT1; ga.Bh[1] = WvT2; ga.Bz[0] = 0; ga.Bz[1] = 0;
    ga.O0[0] = Mb; ga.O0[1] = Mb;
    gemm_tn2<EP_BF16, false, false><<<dim3(4, 4, 16), 256, 0, stream>>>(ga, 512, 512, 512, 262144);
  }
  {
    GArgs ga = {};
    ga.Ah[0] = xT1; ga.Ah[1] = xT2; ga.Az[0] = 2097152; ga.Az[1] = 2097152;
    ga.Bh[0] = Mb; ga.Bh[1] = Mb + 2097152; ga.Bz[0] = 262144; ga.Bz[1] = 262144;
    ga.O0[0] = xcatA; ga.O0[1] = xcatB;
    ga.f0[0] = mb; ga.f0[1] = mb + 4096;
    ga.f1[0] = gates; ga.f1[1] = gates + 8;
    ga.rptr[0] = xT1; ga.rptr[1] = xT2;
    gemm_tn2<EP_XCAT, false, true><<<2048, 256, 0, stream>>>(ga, 512, 512, 512, 0);
  }

  k_conv32<<<256, 512, 0, stream>>>(wcp, xcatA, xcatB, ybuf, bnsum, bnsum2);
  k_bnapply<<<4096, 256, 0, stream>>>(ybuf, bnsum, bnsum2, gamma, beta);
}

// Round 11
// 598.962 us; speedup vs baseline: 1.0863x; 1.0863x over previous
//
#include <hip/hip_runtime.h>

// CrossAtt via Gram trick: logits = Wk·(x1·x2^T)·Wq^T; out = (attn^T·Wv)·x.
// Round 11: revert conv to r9's 16x16x32 pipelined kernel (32x32 regressed:
// 4-way LDS read conflict inherent to 32-row frags on 8-slot swizzle + too few
// independent acc chains). This file == round 9 (best known: 601 us).

typedef unsigned short u16;
typedef unsigned int u32;
typedef float f32x4 __attribute__((ext_vector_type(4)));
typedef short bf16x8 __attribute__((ext_vector_type(8)));

#define DEV __device__ __forceinline__

DEV u16 f2bf(float f) {
  u32 u = __float_as_uint(f);
  return (u16)((u + 0x7fffu + ((u >> 16) & 1u)) >> 16);  // RNE
}
DEV float bf2f(u16 u) { return __uint_as_float(((u32)u) << 16); }

DEV void gload_lds16(const void* g, void* l) {
  __builtin_amdgcn_global_load_lds(
      (const __attribute__((address_space(1))) void*)g,
      (__attribute__((address_space(3))) void*)l, 16, 0, 0);
}

// stage a 128x32 bf16 tile; LDS slot s of row r holds global slot s^(r&3)
DEV void stage_tile(u16* L, const u16* src, int row0, long ld, int k0, int wid, int lane) {
  int rr = lane >> 2;
  int cc = (((lane & 3) ^ (rr & 3)) << 3);
#pragma unroll
  for (int j = 0; j < 2; ++j) {
    int chunk = j * 4 + wid;
    const u16* g = src + (long)(row0 + chunk * 16 + rr) * ld + (k0 + cc);
    gload_lds16(g, L + chunk * 512);
  }
}

DEV float waveRedSum(float v) {
#pragma unroll
  for (int o = 32; o > 0; o >>= 1) v += __shfl_xor(v, o);
  return v;
}

// ---------------- Gram GEMM, split-K=4 ----------------
__global__ __launch_bounds__(256) void gemm_gramK(const float* __restrict__ X1,
                                                  const float* __restrict__ X2,
                                                  float* __restrict__ parts)
{
  __shared__ __align__(16) u16 lds[4 * 4096];
  const int bid = blockIdx.x;
  const int cid = ((bid & 7) << 6) + (bid >> 3);
  const int z = cid >> 4, xy = cid & 15;
  const int quarter = z >> 3, b = z & 7;
  const int m0 = (xy & 3) * 128, n0 = (xy >> 2) * 128;
  const int tid = threadIdx.x, wid = tid >> 6, lane = tid & 63;
  const int wr = wid >> 1, wc = wid & 1;
  const int r16 = lane & 15;
  const int koff = (((lane >> 4) ^ (r16 & 3)) << 3);
  const float* A = X1 + (long)b * 2097152 + quarter * 1024;
  const float* Bp = X2 + (long)b * 2097152 + quarter * 1024;
  const int sr = tid >> 3;
  const int sc = (tid & 7) * 4;
  const int s8 = (tid & 7) >> 1, hf = tid & 1;
  const int swoff = ((s8 ^ (sr & 3)) << 3) + hf * 4;

  f32x4 acc[4][4];
#pragma unroll
  for (int i = 0; i < 4; ++i)
#pragma unroll
    for (int j = 0; j < 4; ++j) acc[i][j] = (f32x4){0.f, 0.f, 0.f, 0.f};

  for (int k0 = 0; k0 < 1024; k0 += 32) {
    __syncthreads();
#pragma unroll
    for (int rr = 0; rr < 128; rr += 32) {
      float4 va = *(const float4*)&A[(long)(m0 + rr + sr) * 4096 + k0 + sc];
      float4 vb = *(const float4*)&Bp[(long)(n0 + rr + sr) * 4096 + k0 + sc];
      float fa[4] = {va.x, va.y, va.z, va.w};
      float fb[4] = {vb.x, vb.y, vb.z, vb.w};
      u32 pah0 = 0, pah1 = 0, pal0 = 0, pal1 = 0;
      u32 pbh0 = 0, pbh1 = 0, pbl0 = 0, pbl1 = 0;
#pragma unroll
      for (int e = 0; e < 2; ++e) {
        u16 h = f2bf(fa[e]);      pah0 |= ((u32)h) << (16 * e);
        u16 lo = f2bf(fa[e] - bf2f(h)); pal0 |= ((u32)lo) << (16 * e);
        h = f2bf(fa[e + 2]);      pah1 |= ((u32)h) << (16 * e);
        lo = f2bf(fa[e + 2] - bf2f(h)); pal1 |= ((u32)lo) << (16 * e);
        h = f2bf(fb[e]);          pbh0 |= ((u32)h) << (16 * e);
        lo = f2bf(fb[e] - bf2f(h)); pbl0 |= ((u32)lo) << (16 * e);
        h = f2bf(fb[e + 2]);      pbh1 |= ((u32)h) << (16 * e);
        lo = f2bf(fb[e + 2] - bf2f(h)); pbl1 |= ((u32)lo) << (16 * e);
      }
      int off = (rr + sr) * 32 + swoff;
      *(uint2*)&lds[off]         = make_uint2(pah0, pah1);
      *(uint2*)&lds[4096 + off]  = make_uint2(pal0, pal1);
      *(uint2*)&lds[8192 + off]  = make_uint2(pbh0, pbh1);
      *(uint2*)&lds[12288 + off] = make_uint2(pbl0, pbl1);
    }
    __syncthreads();
    bf16x8 ah[4], al[4], bh[4], bl[4];
#pragma unroll
    for (int mi = 0; mi < 4; ++mi) {
      ah[mi] = *(const bf16x8*)&lds[(wr * 64 + mi * 16 + r16) * 32 + koff];
      al[mi] = *(const bf16x8*)&lds[4096 + (wr * 64 + mi * 16 + r16) * 32 + koff];
    }
#pragma unroll
    for (int nj = 0; nj < 4; ++nj) {
      bh[nj] = *(const bf16x8*)&lds[8192 + (wc * 64 + nj * 16 + r16) * 32 + koff];
      bl[nj] = *(const bf16x8*)&lds[12288 + (wc * 64 + nj * 16 + r16) * 32 + koff];
    }
#pragma unroll
    for (int mi = 0; mi < 4; ++mi)
#pragma unroll
      for (int nj = 0; nj < 4; ++nj) {
        acc[mi][nj] = __builtin_amdgcn_mfma_f32_16x16x32_bf16(ah[mi], bh[nj], acc[mi][nj], 0, 0, 0);
        acc[mi][nj] = __builtin_amdgcn_mfma_f32_16x16x32_bf16(ah[mi], bl[nj], acc[mi][nj], 0, 0, 0);
        acc[mi][nj] = __builtin_amdgcn_mfma_f32_16x16x32_bf16(al[mi], bh[nj], acc[mi][nj], 0, 0, 0);
      }
  }

  const int rq = lane >> 4;
  float* O = parts + (long)z * 262144;
#pragma unroll
  for (int mi = 0; mi < 4; ++mi)
#pragma unroll
    for (int nj = 0; nj < 4; ++nj)
#pragma unroll
      for (int i = 0; i < 4; ++i) {
        int row = m0 + wr * 64 + mi * 16 + rq * 4 + i;
        int col = n0 + wc * 64 + nj * 16 + r16;
        O[(long)row * 512 + col] = acc[mi][nj][i];
      }
}

__global__ __launch_bounds__(256) void k_gsplit(const float* __restrict__ parts,
                                                u16* __restrict__ Gh, u16* __restrict__ Gl)
{
  for (long i = (long)blockIdx.x * 256 + threadIdx.x; i < 2097152; i += (long)gridDim.x * 256) {
    float v = parts[i] + parts[i + 2097152] + parts[i + 4194304] + parts[i + 6291456];
    u16 h = f2bf(v);
    Gh[i] = h;
    Gl[i] = f2bf(v - bf2f(h));
  }
}

// ---------------- branch-merged TN GEMM ----------------
constexpr int EP_SPLIT = 0, EP_LOGITS = 1, EP_BF16 = 2, EP_XCAT = 3;

struct GArgs {
  const u16* Ah[2]; const u16* Al[2];
  const u16* Bh[2]; const u16* Bl[2];
  long Az[2], Bz[2];
  void* O0[2]; void* O1[2];
  const float* f0[2]; const float* f1[2];
  const float* f2[2]; const float* f3[2];
  const u16* rptr[2];
};

template <int EP, bool SPLIT3, bool FLAT>
__global__ __launch_bounds__(256) void gemm_tn2(GArgs ga, int lda, int ldb, int K, long Oz)
{
  __shared__ __align__(16) u16 lds[(SPLIT3 ? 4 : 2) * 4096];
  int bx, by, z;
  if constexpr (FLAT) {
    const int cid = ((blockIdx.x & 7) << 8) + (blockIdx.x >> 3);
    z = cid >> 7;
    const int xy = cid & 127;
    bx = xy >> 2; by = xy & 3;
  } else {
    bx = blockIdx.x; by = blockIdx.y; z = blockIdx.z;
  }
  const int br = z >> 3, b = z & 7;
  const u16* pAh = ga.Ah[br] + (long)b * ga.Az[br];
  const u16* pBh = ga.Bh[br] + (long)b * ga.Bz[br];
  const u16* pAl = SPLIT3 ? ga.Al[br] + (long)b * ga.Az[br] : nullptr;
  const u16* pBl = SPLIT3 ? ga.Bl[br] + (long)b * ga.Bz[br] : nullptr;
  const int m0 = bx * 128, n0 = by * 128;
  const int tid = threadIdx.x, wid = tid >> 6, lane = tid & 63;
  const int wr = wid >> 1, wc = wid & 1;
  const int r16 = lane & 15;
  const int koff = (((lane >> 4) ^ (r16 & 3)) << 3);

  f32x4 acc[4][4];
#pragma unroll
  for (int i = 0; i < 4; ++i)
#pragma unroll
    for (int j = 0; j < 4; ++j) acc[i][j] = (f32x4){0.f, 0.f, 0.f, 0.f};

  for (int k0 = 0; k0 < K; k0 += 32) {
    __syncthreads();
    stage_tile(lds, pAh, m0, lda, k0, wid, lane);
    stage_tile(lds + 4096, pBh, n0, ldb, k0, wid, lane);
    if constexpr (SPLIT3) {
      stage_tile(lds + 8192, pAl, m0, lda, k0, wid, lane);
      stage_tile(lds + 12288, pBl, n0, ldb, k0, wid, lane);
    }
    __syncthreads();
    bf16x8 af[4], bfh[4], af2[4], bf2_[4];
#pragma unroll
    for (int mi = 0; mi < 4; ++mi)
      af[mi] = *(const bf16x8*)&lds[(wr * 64 + mi * 16 + r16) * 32 + koff];
#pragma unroll
    for (int nj = 0; nj < 4; ++nj)
      bfh[nj] = *(const bf16x8*)&lds[4096 + (wc * 64 + nj * 16 + r16) * 32 + koff];
    if constexpr (SPLIT3) {
#pragma unroll
      for (int mi = 0; mi < 4; ++mi)
        af2[mi] = *(const bf16x8*)&lds[8192 + (wr * 64 + mi * 16 + r16) * 32 + koff];
#pragma unroll
      for (int nj = 0; nj < 4; ++nj)
        bf2_[nj] = *(const bf16x8*)&lds[12288 + (wc * 64 + nj * 16 + r16) * 32 + koff];
    }
#pragma unroll
    for (int mi = 0; mi < 4; ++mi)
#pragma unroll
      for (int nj = 0; nj < 4; ++nj) {
        acc[mi][nj] = __builtin_amdgcn_mfma_f32_16x16x32_bf16(af[mi], bfh[nj], acc[mi][nj], 0, 0, 0);
        if constexpr (SPLIT3) {
          acc[mi][nj] = __builtin_amdgcn_mfma_f32_16x16x32_bf16(af[mi], bf2_[nj], acc[mi][nj], 0, 0, 0);
          acc[mi][nj] = __builtin_amdgcn_mfma_f32_16x16x32_bf16(af2[mi], bfh[nj], acc[mi][nj], 0, 0, 0);
        }
      }
  }

  const int rq = lane >> 4;
  const long off = (long)z * Oz;
  float g = 0.f;
  if constexpr (EP == EP_XCAT) g = ga.f1[br][b];
#pragma unroll
  for (int mi = 0; mi < 4; ++mi)
#pragma unroll
    for (int nj = 0; nj < 4; ++nj)
#pragma unroll
      for (int i = 0; i < 4; ++i) {
        int row = m0 + wr * 64 + mi * 16 + rq * 4 + i;
        int col = n0 + wc * 64 + nj * 16 + r16;
        float v = acc[mi][nj][i];
        if constexpr (EP == EP_SPLIT) {
          long idx = off + (long)row * 512 + col;
          u16 h = f2bf(v);
          ((u16*)ga.O0[br])[idx] = h;
          ((u16*)ga.O1[br])[idx] = f2bf(v - bf2f(h));
        } else if constexpr (EP == EP_LOGITS) {
          v += ga.f0[br][row] * ga.f3[br][b * 512 + col] + ga.f1[br][col] * ga.f2[br][b * 512 + row];
          ((float*)ga.O0[br])[off + (long)row * 512 + col] = v;
        } else if constexpr (EP == EP_BF16) {
          ((u16*)ga.O0[br])[off + (long)row * 512 + col] = f2bf(v);
        } else {
          float val = (v + ga.f0[br][b * 512 + col]) * g +
                      bf2f(ga.rptr[br][(long)b * 2097152 + (long)row * 512 + col]);
          int yy = row >> 6, xx = row & 63;
          long oidx = ((long)(b * 66 + yy + 1) * 66 + (xx + 1)) * 512 + col;
          ((u16*)ga.O0[br])[oidx] = f2bf(val);
        }
      }
}

// ---------------- conv3x3 (pipelined 16x16x32, r9 best) ----------------
#define MF(a, b, c) __builtin_amdgcn_mfma_f32_16x16x32_bf16(a, b, c, 0, 0, 0)
#define SCHEDB() __builtin_amdgcn_sched_barrier(0)
#define BAR() __builtin_amdgcn_s_barrier()
#define STG_B(QB, i) gload_lds16(xb + sbo[i] + kko, &lds[(QB) + ldsB0 + (i) * 4096])
#define STG_A(QB, i) gload_lds16(Arow + (i) * 294912L + Aoff, &lds[(QB) + ldsA0 + (i) * 2048])

#define RD_A(d, fmb)                                                        \
  d##0 = *(const bf16x8*)&lds[pBase + aRd + (fmb) * 1024 + sxa0];           \
  d##1 = *(const bf16x8*)&lds[pBase + aRd + (fmb) * 1024 + sxa1];           \
  d##2 = *(const bf16x8*)&lds[pBase + aRd + ((fmb) + 1) * 1024 + sxa0];     \
  d##3 = *(const bf16x8*)&lds[pBase + aRd + ((fmb) + 1) * 1024 + sxa1];

#define MM(jj, r)                                                           \
  __builtin_amdgcn_s_setprio(1);                                            \
  _Pragma("unroll")                                                         \
  for (int fn = 0; fn < 4; ++fn) {                                          \
    acc[2 * (jj)][fn] = MF(r##0, bq[fn][0], acc[2 * (jj)][fn]);             \
    acc[2 * (jj)][fn] = MF(r##1, bq[fn][1], acc[2 * (jj)][fn]);             \
    acc[2 * (jj) + 1][fn] = MF(r##2, bq[fn][0], acc[2 * (jj) + 1][fn]);     \
    acc[2 * (jj) + 1][fn] = MF(r##3, bq[fn][1], acc[2 * (jj) + 1][fn]);     \
  }                                                                         \
  __builtin_amdgcn_s_setprio(0);                                            \
  SCHEDB();

__global__ __launch_bounds__(512, 2) void k_conv8(const u16* __restrict__ W,
                                                  const u16* __restrict__ xA,
                                                  const u16* __restrict__ xB,
                                                  float* __restrict__ y,
                                                  float* __restrict__ bnsum,
                                                  float* __restrict__ bnsum2)
{
  __shared__ __align__(16) u16 lds[65536];
  const int cid = ((blockIdx.x & 7) << 5) + (blockIdx.x >> 3);
  const int bz = cid >> 5, mx = (cid >> 4) & 1, ny = cid & 15;
  const int m0 = mx * 256, n0 = ny * 256;
  const long zoff = (long)bz * 2230272;

  const int tid = threadIdx.x;
  const int w = tid >> 6, l = tid & 63;
  const int wr = w >> 2, wcn = w & 3, wl = w & 3;
  const int lr = l >> 3, l7 = l & 7, l15 = l & 15, l4 = l >> 4;
  const int ss8 = (l7 ^ lr) << 3;

  long sbo[4];
#pragma unroll
  for (int i = 0; i < 4; ++i) {
    int n = n0 + i * 64 + w * 8 + lr;
    sbo[i] = (long)((n >> 6) * 66 + (n & 63)) * 512;
  }
  const u16* Arow = W + (long)(m0 + wr * 128 + wl * 8 + lr) * 9216 + ss8;
  const int ldsA0 = wr * 8192 + wl * 512;
  const int ldsB0 = 16384 + w * 512;
  const int sxa0 = (l4 ^ l7) << 3;
  const int sxa1 = ((l4 | 4) ^ l7) << 3;
  const int aRd = wr * 8192 + l15 * 64;
  const int bRd = 16384 + wcn * 4096 + l15 * 64;

  f32x4 acc[8][4];
#pragma unroll
  for (int i = 0; i < 8; ++i)
#pragma unroll
    for (int j = 0; j < 4; ++j) acc[i][j] = (f32x4){0.f, 0.f, 0.f, 0.f};

  {
    const u16* xb = xA + zoff;
    const long kko = ss8;
    const long Aoff = 0;
    STG_B(0, 0); STG_B(0, 1); STG_B(0, 2); STG_B(0, 3);
    STG_A(0, 0); STG_A(0, 1); STG_A(0, 2); STG_A(0, 3);
  }

  for (int t = 0; t < 144; ++t) {
    const int pBase = (t & 1) << 15;
    const int qBase = pBase ^ 32768;
    const int tau = t + 1;
    const bool pf = tau < 144;
    const int ccc = tau / 9;
    const int tap = tau - ccc * 9;
    const int cch = ccc << 6;
    const u16* xb = ((cch & 512) ? xB : xA) + zoff;
    const long kko = (long)((tap / 3) * 66 + (tap % 3)) * 512 + (cch & 511) + ss8;
    const long Aoff = (long)(tap << 10) + cch;
    bf16x8 bq[4][2];
    bf16x8 cA0, cA1, cA2, cA3, nA0, nA1, nA2, nA3;

    if (pf) { STG_B(qBase, 0); STG_B(qBase, 1); asm volatile("s_waitcnt vmcnt(4)" ::: "memory"); }
    else    { asm volatile("s_waitcnt vmcnt(2)" ::: "memory"); }
    BAR(); SCHEDB();
#pragma unroll
    for (int fn = 0; fn < 4; ++fn) {
      bq[fn][0] = *(const bf16x8*)&lds[pBase + bRd + fn * 1024 + sxa0];
      bq[fn][1] = *(const bf16x8*)&lds[pBase + bRd + fn * 1024 + sxa1];
    }
    RD_A(cA, 0)
    RD_A(nA, 2)
    MM(0, cA)
    if (pf) { STG_B(qBase, 2); STG_B(qBase, 3); asm volatile("s_waitcnt vmcnt(5)" ::: "memory"); }
    else    { asm volatile("s_waitcnt vmcnt(1)" ::: "memory"); }
    BAR(); SCHEDB();
    RD_A(cA, 4)
    MM(1, nA)
    if (pf) { STG_A(qBase, 0); STG_A(qBase, 1); asm volatile("s_waitcnt vmcnt(6)" ::: "memory"); }
    else    { asm volatile("s_waitcnt vmcnt(0)" ::: "memory"); }
    BAR(); SCHEDB();
    RD_A(nA, 6)
    MM(2, cA)
    if (pf) { STG_A(qBase, 2); STG_A(qBase, 3); }
    BAR(); SCHEDB();
    MM(3, nA)
  }

#pragma unroll
  for (int fm = 0; fm < 8; ++fm)
#pragma unroll
    for (int fn = 0; fn < 4; ++fn)
#pragma unroll
      for (int i = 0; i < 4; ++i) {
        int row = m0 + wr * 128 + fm * 16 + l4 * 4 + i;
        int col = n0 + wcn * 64 + fn * 16 + l15;
        y[((long)bz * 512 + row) * 4096 + col] = acc[fm][fn][i];
      }

  __syncthreads();
  float* fl = (float*)lds;
#pragma unroll
  for (int fm = 0; fm < 8; ++fm)
#pragma unroll
    for (int i = 0; i < 4; ++i) {
      float s = acc[fm][0][i] + acc[fm][1][i] + acc[fm][2][i] + acc[fm][3][i];
      float s2 = acc[fm][0][i] * acc[fm][0][i] + acc[fm][1][i] * acc[fm][1][i] +
                 acc[fm][2][i] * acc[fm][2][i] + acc[fm][3][i] * acc[fm][3][i];
#pragma unroll
      for (int m = 1; m < 16; m <<= 1) { s += __shfl_xor(s, m); s2 += __shfl_xor(s2, m); }
      if (l15 == 0) {
        int r = wr * 128 + fm * 16 + l4 * 4 + i;
        fl[r * 4 + wcn] = s;
        fl[1024 + r * 4 + wcn] = s2;
      }
    }
  __syncthreads();
  {
    int r = tid & 255;
    int which = tid >> 8;
    const float* p = fl + which * 1024 + r * 4;
    float v = p[0] + p[1] + p[2] + p[3];
    atomicAdd((which ? bnsum2 : bnsum) + m0 + r, v);
  }
}

// ---------------- mega-prep ----------------
struct PrepArgs {
  const float* wv1; const float* wv2;
  u16* WvT1; u16* WvT2;
  const float* s[4]; u16* h[4]; u16* l[4];
  const float* wcat; u16* wcp;
  u16* xcat;
  float* rsum; float* bnsum; float* mbz;
};

__global__ __launch_bounds__(256) void k_mprep(PrepArgs a)
{
  __shared__ __align__(16) float shbuf[9261];
  const int bx = blockIdx.x;
  const int tid = threadIdx.x;
  if (bx < 128) {
    const float* src = (bx < 64) ? a.wv1 : a.wv2;
    u16* dst = (bx < 64) ? a.WvT1 : a.WvT2;
    const int t8 = bx & 63;
    const int c0 = (t8 & 7) * 64, r0 = (t8 >> 3) * 64;
#pragma unroll
    for (int it = 0; it < 4; ++it) {
      int rr = it * 16 + (tid >> 4);
      int cc = (tid & 15) * 4;
      float4 v = *(const float4*)&src[(long)(r0 + rr) * 512 + c0 + cc];
      shbuf[rr * 65 + cc] = v.x; shbuf[rr * 65 + cc + 1] = v.y;
      shbuf[rr * 65 + cc + 2] = v.z; shbuf[rr * 65 + cc + 3] = v.w;
    }
    __syncthreads();
    int nr = tid >> 2, cs = (tid & 3) * 16;
    u16 hh[16] __attribute__((aligned(16)));
#pragma unroll
    for (int j = 0; j < 16; ++j) hh[j] = f2bf(shbuf[(cs + j) * 65 + nr]);
    long d = (long)(c0 + nr) * 512 + r0 + cs;
    *(uint4*)&dst[d] = *(const uint4*)&hh[0];
    *(uint4*)&dst[d + 8] = *(const uint4*)&hh[8];
  } else if (bx < 1152) {
    int which = (bx - 128) >> 8;
    const float* s = a.s[which];
    u16* h = a.h[which];
    u16* l = a.l[which];
    for (int i = ((bx - 128) & 255) * 256 + tid; i < 262144; i += 65536) {
      float v = s[i];
      u16 hh = f2bf(v);
      h[i] = hh;
      l[i] = f2bf(v - bf2f(hh));
    }
  } else if (bx < 1664) {
    const int o = bx - 1152;
    const float* s = a.wcat + (long)o * 9216;
#pragma unroll
    for (int it = 0; it < 9; ++it) {
      int f4 = it * 256 + tid;
      float4 v = *(const float4*)&s[f4 * 4];
      float va[4] = {v.x, v.y, v.z, v.w};
      int f = f4 * 4;
#pragma unroll
      for (int e = 0; e < 4; ++e) {
        int ic = (f + e) / 9, tp = (f + e) - ic * 9;
        shbuf[tp * 1029 + ic] = va[e];
      }
    }
    __syncthreads();
    u16* d = a.wcp + (long)o * 9216;
#pragma unroll
    for (int tp = 0; tp < 9; ++tp)
#pragma unroll
      for (int c = 0; c < 4; ++c) {
        int ic = c * 256 + tid;
        d[tp * 1024 + ic] = f2bf(shbuf[tp * 1029 + ic]);
      }
  } else if (bx < 1680) {
    const long base = (long)(bx - 1664) * 2230272;
    const uint4 z4 = make_uint4(0, 0, 0, 0);
    for (int i = tid; i < 8448; i += 256) {
      long off = (i < 4224) ? (long)i * 8 : (long)65 * 66 * 512 + (long)(i - 4224) * 8;
      *(uint4*)&a.xcat[base + off] = z4;
    }
    for (int i = tid; i < 8192; i += 256) {
      int y = 1 + (i >> 7);
      int xsel = (i >> 6) & 1;
      int v = i & 63;
      long off = ((long)y * 66 + (xsel ? 65 : 0)) * 512 + (long)v * 8;
      *(uint4*)&a.xcat[base + off] = z4;
    }
  } else {
    float4 f4 = {0.f, 0.f, 0.f, 0.f};
    for (int i = tid; i < 2048; i += 256) ((float4*)a.rsum)[i] = f4;
    for (int i = tid; i < 256; i += 256) ((float4*)a.bnsum)[i] = f4;
    for (int i = tid; i < 2048; i += 256) ((float4*)a.mbz)[i] = f4;
  }
}

// ---------------- prep: transpose both inputs + gate rowsums ----------------
__global__ __launch_bounds__(256) void k_prep(const float* __restrict__ in1,
                                              const float* __restrict__ in2,
                                              u16* __restrict__ xT1, u16* __restrict__ xT2,
                                              float* __restrict__ rsum)
{
  __shared__ float t[64][65];
  const int zz = blockIdx.z;
  const int inp = zz >> 3, b = zz & 7;
  const int cb = blockIdx.y, nb = blockIdx.x;
  const float* s = (inp ? in2 : in1) + (long)b * 2097152;
  u16* xT = inp ? xT2 : xT1;
  float* rs = rsum + inp * 4096;
  const int tid = threadIdx.x;
#pragma unroll
  for (int it = 0; it < 4; ++it) {
    int cr = it * 16 + (tid >> 4);
    int nc = (tid & 15) * 4;
    float4 v = *(const float4*)&s[(long)(cb * 64 + cr) * 4096 + nb * 64 + nc];
    t[cr][nc] = v.x; t[cr][nc + 1] = v.y; t[cr][nc + 2] = v.z; t[cr][nc + 3] = v.w;
  }
  __syncthreads();
  int nr = tid >> 2, cs = (tid & 3) * 16;
  u16 hh[16] __attribute__((aligned(16)));
#pragma unroll
  for (int j = 0; j < 16; ++j) hh[j] = f2bf(t[cs + j][nr]);
  long d = (long)b * 2097152 + (long)(nb * 64 + nr) * 512 + cb * 64 + cs;
  *(uint4*)&xT[d] = *(const uint4*)&hh[0];
  *(uint4*)&xT[d + 8] = *(const uint4*)&hh[8];
  if (tid < 64) {
    float sum = 0.f;
#pragma unroll 8
    for (int j = 0; j < 64; ++j) sum += t[tid][j];
    atomicAdd(&rs[b * 512 + tid + cb * 64], sum);
  }
}

// ---------------- skq + gate ----------------
__global__ __launch_bounds__(256) void k_skq(const float* __restrict__ wk1, const float* __restrict__ wq2,
                                             const float* __restrict__ wk2, const float* __restrict__ wq1,
                                             const float* __restrict__ bq2, const float* __restrict__ bq1,
                                             const float* __restrict__ wlin,
                                             const float* __restrict__ rowsum,
                                             float* __restrict__ S, float* __restrict__ gates)
{
  int which = blockIdx.y, b = blockIdx.z;
  int lane = threadIdx.x & 63;
  if (which == 4) {
    if (blockIdx.x < 2 && threadIdx.x < 64) {
      int inp = blockIdx.x;
      float s = 0.f;
      for (int c = lane; c < 512; c += 64) s += rowsum[inp * 4096 + b * 512 + c] * wlin[c];
      s = waveRedSum(s);
      if (lane == 0) gates[inp * 8 + b] = 1.f / (1.f + __expf(-s / 4096.f));
    }
    return;
  }
  int row = blockIdx.x * 4 + (threadIdx.x >> 6);
  const float* W; const float* rs; const float* bias = nullptr;
  if (which == 0)      { W = wk1; rs = rowsum + b * 512; }
  else if (which == 1) { W = wq2; rs = rowsum + 4096 + b * 512; bias = bq2; }
  else if (which == 2) { W = wk2; rs = rowsum + 4096 + b * 512; }
  else                 { W = wq1; rs = rowsum + b * 512; bias = bq1; }
  float s = 0.f;
  for (int i = lane; i < 512; i += 64) s += W[row * 512 + i] * rs[i];
  s = waveRedSum(s);
  if (lane == 0) S[(which * 8 + b) * 512 + row] = s + (bias ? 4096.f * bias[row] : 0.f);
}

// ---------------- softmax + fused mbias partials ----------------
__global__ __launch_bounds__(256) void k_softmaxT(const float* __restrict__ L,
                                                  u16* __restrict__ attnT,
                                                  const float* __restrict__ bv1,
                                                  const float* __restrict__ bv2,
                                                  float* __restrict__ mb)
{
  const int bid = blockIdx.x;
  const int z = bid >> 4, rg = bid & 15;
  const int w = threadIdx.x >> 6, lane = threadIdx.x & 63;
  const int a0 = rg * 32 + w * 8;
  const float* Lz = L + (long)z * 262144;
  const float* bv = (z >= 8) ? bv2 : bv1;
  u16* Az = attnT + (long)z * 262144;
  u32 pk[8][4] = {};
  float pmb[8] = {};
#pragma unroll
  for (int it = 0; it < 8; ++it) {
    long base = (long)(a0 + it) * 512 + lane * 8;
    float4 p0 = *(const float4*)&Lz[base], p1 = *(const float4*)&Lz[base + 4];
    float v[8] = {p0.x, p0.y, p0.z, p0.w, p1.x, p1.y, p1.z, p1.w};
    float m = v[0];
#pragma unroll
    for (int j = 1; j < 8; ++j) m = fmaxf(m, v[j]);
#pragma unroll
    for (int o = 32; o > 0; o >>= 1) m = fmaxf(m, __shfl_xor(m, o));
    float e[8], s = 0.f;
#pragma unroll
    for (int j = 0; j < 8; ++j) { e[j] = __expf(v[j] - m); s += e[j]; }
    s = waveRedSum(s);
    float inv = 1.f / s;
    float bvv = bv[a0 + it];
#pragma unroll
    for (int j = 0; j < 8; ++j) {
      float p = e[j] * inv;
      pk[j][it >> 1] |= ((u32)f2bf(p)) << ((it & 1) * 16);
      pmb[j] += p * bvv;
    }
  }
#pragma unroll
  for (int j = 0; j < 8; ++j) {
    int c = lane * 8 + j;
    *(uint4*)&Az[(long)c * 512 + a0] = make_uint4(pk[j][0], pk[j][1], pk[j][2], pk[j][3]);
    atomicAdd(&mb[z * 512 + c], pmb[j]);
  }
}

// ---------------- BN apply (stats inlined) + ReLU ----------------
__global__ __launch_bounds__(256) void k_bnapply(float* __restrict__ y,
                                                 const float* __restrict__ bnsum,
                                                 const float* __restrict__ bnsum2,
                                                 const float* __restrict__ gamma,
                                                 const float* __restrict__ beta)
{
  const long n = 16777216;
  for (long i = ((long)blockIdx.x * 256 + threadIdx.x) * 4; i < n; i += (long)gridDim.x * 1024) {
    float4 v = *(const float4*)&y[i];
    int o = (int)((i >> 12) & 511);
    float mean = bnsum[o] * (1.f / 32768.f);
    float var = bnsum2[o] * (1.f / 32768.f) - mean * mean;
    float a = gamma[o] * rsqrtf(var + 1e-5f);
    float c = beta[o] - mean * a;
    v.x = fmaxf(v.x * a + c, 0.f);
    v.y = fmaxf(v.y * a + c, 0.f);
    v.z = fmaxf(v.z * a + c, 0.f);
    v.w = fmaxf(v.w * a + c, 0.f);
    *(float4*)&y[i] = v;
  }
}

// ================= host =================
extern "C" void kernel_launch(void* const* d_in, const int* in_sizes, int n_in,
                              void* d_out, int out_size, void* d_ws, size_t ws_size,
                              hipStream_t stream)
{
  (void)in_sizes; (void)n_in; (void)out_size; (void)ws_size;
  const float* in1 = (const float*)d_in[0];
  const float* in2 = (const float*)d_in[1];
  const float* wq1 = (const float*)d_in[2];  const float* bq1 = (const float*)d_in[3];
  const float* wk1 = (const float*)d_in[4];  const float* bk1 = (const float*)d_in[5];
  const float* wv1 = (const float*)d_in[6];  const float* bv1 = (const float*)d_in[7];
  const float* wq2 = (const float*)d_in[8];  const float* bq2 = (const float*)d_in[9];
  const float* wk2 = (const float*)d_in[10]; const float* bk2 = (const float*)d_in[11];
  const float* wv2 = (const float*)d_in[12]; const float* bv2 = (const float*)d_in[13];
  const float* wlin  = (const float*)d_in[14];
  const float* wcat  = (const float*)d_in[15];
  const float* gamma = (const float*)d_in[16];
  const float* beta  = (const float*)d_in[17];

  char* ws = (char*)d_ws;
  const size_t MB = 1024ull * 1024ull;
  u16* Gh     = (u16*)(ws + 0 * MB);
  u16* Gl     = (u16*)(ws + 4 * MB);
  u16* Mb     = (u16*)(ws + 0 * MB);
  u16* Uh     = (u16*)(ws + 8 * MB);
  u16* attnT  = (u16*)(ws + 8 * MB);
  u16* Ul     = (u16*)(ws + 16 * MB);
  float* logits = (float*)(ws + 24 * MB);
  float* parts  = (float*)(ws + 8 * MB);
  u16* xcatA  = (u16*)(ws + 40 * MB);
  u16* xcatB  = xcatA + 8L * 2230272;
  u16* wcp    = (u16*)(ws + 112 * MB);
  u16* wsp    = (u16*)(ws + 122 * MB);
  u16* WvT1   = (u16*)(ws + 126 * MB);
  u16* WvT2   = WvT1 + 262144;
  float* rowsum = (float*)(ws + 127 * MB);
  float* gates  = (float*)(ws + 127 * MB + 32 * 1024);
  float* S      = (float*)(ws + 127 * MB + 36 * 1024);
  float* mb     = (float*)(ws + 127 * MB + 100 * 1024);
  float* bnsum  = (float*)(ws + 127 * MB + 132 * 1024);
  float* bnsum2 = (float*)(ws + 127 * MB + 134 * 1024);

  u16* wq1h = wsp + 0 * 262144; u16* wq1l = wsp + 1 * 262144;
  u16* wq2h = wsp + 2 * 262144; u16* wq2l = wsp + 3 * 262144;
  u16* wk1h = wsp + 4 * 262144; u16* wk1l = wsp + 5 * 262144;
  u16* wk2h = wsp + 6 * 262144; u16* wk2l = wsp + 7 * 262144;

  u16* xT1 = (u16*)d_out;
  u16* xT2 = (u16*)d_out + 16777216;
  float* ybuf = (float*)d_out;

  {
    PrepArgs pa;
    pa.wv1 = wv1; pa.wv2 = wv2; pa.WvT1 = WvT1; pa.WvT2 = WvT2;
    pa.s[0] = wq1; pa.h[0] = wq1h; pa.l[0] = wq1l;
    pa.s[1] = wq2; pa.h[1] = wq2h; pa.l[1] = wq2l;
    pa.s[2] = wk1; pa.h[2] = wk1h; pa.l[2] = wk1l;
    pa.s[3] = wk2; pa.h[3] = wk2h; pa.l[3] = wk2l;
    pa.wcat = wcat; pa.wcp = wcp;
    pa.xcat = xcatA;
    pa.rsum = rowsum; pa.bnsum = bnsum; pa.mbz = mb;
    k_mprep<<<1681, 256, 0, stream>>>(pa);
  }
  k_prep<<<dim3(64, 8, 16), 256, 0, stream>>>(in1, in2, xT1, xT2, rowsum);
  k_skq<<<dim3(128, 5, 8), 256, 0, stream>>>(wk1, wq2, wk2, wq1, bq2, bq1, wlin, rowsum, S, gates);

  gemm_gramK<<<512, 256, 0, stream>>>(in1, in2, parts);
  k_gsplit<<<2048, 256, 0, stream>>>(parts, Gh, Gl);

  {
    GArgs ga = {};
    ga.Ah[0] = wq2h; ga.Al[0] = wq2l; ga.Ah[1] = wk2h; ga.Al[1] = wk2l;
    ga.Az[0] = 0; ga.Az[1] = 0;
    ga.Bh[0] = Gh; ga.Bl[0] = Gl; ga.Bh[1] = Gh; ga.Bl[1] = Gl;
    ga.Bz[0] = 262144; ga.Bz[1] = 262144;
    ga.O0[0] = Uh; ga.O0[1] = Uh; ga.O1[0] = Ul; ga.O1[1] = Ul;
    gemm_tn2<EP_SPLIT, true, false><<<dim3(4, 4, 16), 256, 0, stream>>>(ga, 512, 512, 512, 262144);
  }
  {
    GArgs ga = {};
    ga.Ah[0] = wk1h; ga.Al[0] = wk1l; ga.Az[0] = 0;
    ga.Ah[1] = Uh + 2097152; ga.Al[1] = Ul + 2097152; ga.Az[1] = 262144;
    ga.Bh[0] = Uh; ga.Bl[0] = Ul; ga.Bz[0] = 262144;
    ga.Bh[1] = wq1h; ga.Bl[1] = wq1l; ga.Bz[1] = 0;
    ga.O0[0] = logits; ga.O0[1] = logits;
    ga.f0[0] = bk1; ga.f1[0] = bq2; ga.f2[0] = S;        ga.f3[0] = S + 4096;
    ga.f0[1] = bk2; ga.f1[1] = bq1; ga.f2[1] = S + 8192; ga.f3[1] = S + 12288;
    gemm_tn2<EP_LOGITS, true, false><<<dim3(4, 4, 16), 256, 0, stream>>>(ga, 512, 512, 512, 262144);
  }
  k_softmaxT<<<256, 256, 0, stream>>>(logits, attnT, bv1, bv2, mb);
  {
    GArgs ga = {};
    ga.Ah[0] = attnT; ga.Ah[1] = attnT + 2097152;
    ga.Az[0] = 262144; ga.Az[1] = 262144;
    ga.Bh[0] = WvT1; ga.Bh[1] = WvT2; ga.Bz[0] = 0; ga.Bz[1] = 0;
    ga.O0[0] = Mb; ga.O0[1] = Mb;
    gemm_tn2<EP_BF16, false, false><<<dim3(4, 4, 16), 256, 0, stream>>>(ga, 512, 512, 512, 262144);
  }
  {
    GArgs ga = {};
    ga.Ah[0] = xT1; ga.Ah[1] = xT2; ga.Az[0] = 2097152; ga.Az[1] = 2097152;
    ga.Bh[0] = Mb; ga.Bh[1] = Mb + 2097152; ga.Bz[0] = 262144; ga.Bz[1] = 262144;
    ga.O0[0] = xcatA; ga.O0[1] = xcatB;
    ga.f0[0] = mb; ga.f0[1] = mb + 4096;
    ga.f1[0] = gates; ga.f1[1] = gates + 8;
    ga.rptr[0] = xT1; ga.rptr[1] = xT2;
    gemm_tn2<EP_XCAT, false, true><<<2048, 256, 0, stream>>>(ga, 512, 512, 512, 0);
  }

  k_conv8<<<256, 512, 0, stream>>>(wcp, xcatA, xcatB, ybuf, bnsum, bnsum2);
  k_bnapply<<<4096, 256, 0, stream>>>(ybuf, bnsum, bnsum2, gamma, beta);
}